// Round 2
// baseline (397.481 us; speedup 1.0000x reference)
//
#include <hip/hip_runtime.h>
#include <stdint.h>
#include <stddef.h>

// Problem constants
#define SEQ    4096
#define DMODEL 768
#define NHEAD  12
#define DHEAD  64
// (1/sqrt(DHEAD)) * log2(e): fold softmax scale AND base-2 conversion into Q
#define QSCALE 0.18033688011112042f

typedef __attribute__((ext_vector_type(8))) short bf16x8;   // 8 bf16 = 4 VGPRs
typedef __attribute__((ext_vector_type(4))) float f32x4;    // MFMA acc

__device__ __forceinline__ unsigned short f2bf(float f) {
    union { float f; unsigned int u; } v; v.f = f;
    unsigned int r = v.u + 0x7FFFu + ((v.u >> 16) & 1u);   // RNE
    return (unsigned short)(r >> 16);
}
__device__ __forceinline__ float bf2f(unsigned short b) {
    union { float f; unsigned int u; } v; v.u = ((unsigned int)b) << 16;
    return v.f;
}
// 8 consecutive fp32 -> bf16x8 (RNE)
__device__ __forceinline__ bf16x8 ld8f_bf(const float* p) {
    f32x4 lo = *(const f32x4*)p;
    f32x4 hi = *(const f32x4*)(p + 4);
    union { bf16x8 v; unsigned short u[8]; } pk;
#pragma unroll
    for (int j = 0; j < 4; j++) { pk.u[j] = f2bf(lo[j]); pk.u[4 + j] = f2bf(hi[j]); }
    return pk.v;
}

// ---------------------------------------------------------------------------
// Runtime dtype detector: reads 1024 u16 of W_in. True-bf16 data -> ~100%
// plausible bf16 exponents; fp32-packed data -> ~58% (low-mantissa halves are
// uniform bits). flag=1 => inputs/outputs are bf16; flag=0 => fp32.
// ---------------------------------------------------------------------------
__global__ void detect_dtype_kernel(const unsigned short* __restrict__ w, int* flag) {
    const int t = threadIdx.x;  // 256 threads x 4 samples
    int pl = 0;
#pragma unroll
    for (int i = 0; i < 4; i++) {
        unsigned short u = w[t * 4 + i];
        unsigned int e = (u >> 7) & 0xFF;
        if ((u & 0x7FFF) == 0 || (e >= 97 && e <= 137)) pl++;  // |v| in ~[2^-30,2^10]
    }
    __shared__ int s[256];
    s[t] = pl;
    __syncthreads();
    for (int off = 128; off > 0; off >>= 1) {
        if (t < off) s[t] += s[t + off];
        __syncthreads();
    }
    if (t == 0) *flag = (s[0] >= 922) ? 1 : 0;   // >=90% of 1024 plausible
}

// ---------------------------------------------------------------------------
// GEMM (BT layout): C[M,N] = A[M,K] * B[N,K]^T + bias.
// 128x128 block, BK=64, 256 threads = 4 waves (2x2), each wave 64x64.
// EPI=0: A/B/bias external (dtype per flag); scatter into Q(scaled)/K/V ws bf16.
// EPI=1: A internal bf16; B/bias external; output external (dtype per flag).
// ---------------------------------------------------------------------------
template <int EPI>
__global__ __launch_bounds__(256, 2) void gemm_bt_kernel(
    const unsigned short* __restrict__ A,
    const unsigned short* __restrict__ B,
    const unsigned short* __restrict__ bias,
    int K, int N, const int* __restrict__ flagp,
    unsigned short* __restrict__ oq,
    unsigned short* __restrict__ ok,
    unsigned short* __restrict__ ov,
    unsigned short* __restrict__ ob)
{
    __shared__ __align__(16) unsigned short As[128 * 72];  // stride 72: conflict-free
    __shared__ __align__(16) unsigned short Bs[128 * 72];

    const bool isbf = (*flagp != 0);
    const int t    = threadIdx.x;
    const int lane = t & 63;
    const int wave = t >> 6;
    const int l15  = lane & 15;
    const int quad = lane >> 4;
    const int wm   = wave >> 1;
    const int wn   = wave & 1;
    const int m0   = blockIdx.y * 128;
    const int n0   = blockIdx.x * 128;

    f32x4 acc[4][4] = {};

    for (int k0 = 0; k0 < K; k0 += 64) {
        bf16x8 ra[4], rb[4];
#pragma unroll
        for (int c = 0; c < 4; c++) {
            int g = c * 256 + t;
            int row = g >> 3, cg = g & 7;
            size_t offa = (size_t)(m0 + row) * K + (k0 + cg * 8);
            size_t offb = (size_t)(n0 + row) * K + (k0 + cg * 8);
            if (EPI == 1 || isbf) ra[c] = *(const bf16x8*)(A + offa);
            else                  ra[c] = ld8f_bf((const float*)A + offa);
            if (isbf) rb[c] = *(const bf16x8*)(B + offb);
            else      rb[c] = ld8f_bf((const float*)B + offb);
        }
        __syncthreads();   // previous iteration's LDS reads done
#pragma unroll
        for (int c = 0; c < 4; c++) {
            int g = c * 256 + t;
            int row = g >> 3, cg = g & 7;
            *(bf16x8*)(As + row * 72 + cg * 8) = ra[c];
            *(bf16x8*)(Bs + row * 72 + cg * 8) = rb[c];
        }
        __syncthreads();
#pragma unroll
        for (int ki = 0; ki < 2; ki++) {
            bf16x8 af[4], bfr[4];
#pragma unroll
            for (int mi = 0; mi < 4; mi++)
                af[mi] = *(const bf16x8*)(As + (wm * 64 + mi * 16 + l15) * 72 + ki * 32 + quad * 8);
#pragma unroll
            for (int ni = 0; ni < 4; ni++)
                bfr[ni] = *(const bf16x8*)(Bs + (wn * 64 + ni * 16 + l15) * 72 + ki * 32 + quad * 8);
#pragma unroll
            for (int mi = 0; mi < 4; mi++)
#pragma unroll
                for (int ni = 0; ni < 4; ni++)
                    acc[mi][ni] = __builtin_amdgcn_mfma_f32_16x16x32_bf16(
                        af[mi], bfr[ni], acc[mi][ni], 0, 0, 0);
        }
    }

    // Epilogue. C/D layout: col = lane&15, row = quad*4 + reg (m89/m91-verified).
    if (EPI == 0) {
        const int nbase = n0 + wn * 64;            // multiple of 64 -> head-aligned
        const int which = nbase / DMODEL;          // 0=q 1=k 2=v (uniform per wave)
        const int hh    = (nbase % DMODEL) >> 6;   // head (uniform per wave)
        unsigned short* dst = (which == 0) ? oq : (which == 1) ? ok : ov;
        const float scl = (which == 0) ? QSCALE : 1.0f;
#pragma unroll
        for (int ni = 0; ni < 4; ni++) {
            const int d  = ni * 16 + l15;
            const float bv = isbf ? bf2f(bias[nbase + d]) : ((const float*)bias)[nbase + d];
#pragma unroll
            for (int mi = 0; mi < 4; mi++) {
                const int mb = m0 + wm * 64 + mi * 16 + quad * 4;
#pragma unroll
                for (int r = 0; r < 4; r++) {
                    float v = (acc[mi][ni][r] + bv) * scl;
                    dst[((size_t)hh * SEQ + (mb + r)) * DHEAD + d] = f2bf(v);
                }
            }
        }
    } else {
#pragma unroll
        for (int ni = 0; ni < 4; ni++) {
            const int n  = n0 + wn * 64 + ni * 16 + l15;
            const float bv = isbf ? bf2f(bias[n]) : ((const float*)bias)[n];
#pragma unroll
            for (int mi = 0; mi < 4; mi++) {
                const int mb = m0 + wm * 64 + mi * 16 + quad * 4;
#pragma unroll
                for (int r = 0; r < 4; r++) {
                    float v = acc[mi][ni][r] + bv;
                    size_t idx = (size_t)(mb + r) * N + n;
                    if (isbf) ob[idx] = f2bf(v);
                    else      ((float*)ob)[idx] = v;
                }
            }
        }
    }
}

// ---------------------------------------------------------------------------
// V transpose: V[h][s][d] -> Vt[h][d][s] (internal bf16), 64x64 tiles via LDS.
// ---------------------------------------------------------------------------
__global__ __launch_bounds__(256) void transpose_v_kernel(
    const unsigned short* __restrict__ V, unsigned short* __restrict__ Vt)
{
    __shared__ unsigned short L[64][65];
    const int h  = blockIdx.y;
    const int s0 = blockIdx.x * 64;
    const int t  = threadIdx.x;
#pragma unroll
    for (int it = 0; it < 16; it++) {
        int s = it * 4 + (t >> 6), d = t & 63;
        L[d][s] = V[((size_t)h * SEQ + s0 + s) * DHEAD + d];
    }
    __syncthreads();
#pragma unroll
    for (int it = 0; it < 16; it++) {
        int d = it * 4 + (t >> 6), s = t & 63;
        Vt[((size_t)h * DHEAD + d) * SEQ + s0 + s] = L[d][s];
    }
}

// ---------------------------------------------------------------------------
// Flash attention, causal. 1 wave / block, 32 Q-rows per block.
// Q pre-scaled by SCALE*log2e -> softmax in base 2. All buffers internal bf16.
// ---------------------------------------------------------------------------
__global__ __launch_bounds__(64) void attn_kernel(
    const unsigned short* __restrict__ Qs,
    const unsigned short* __restrict__ Ks,
    const unsigned short* __restrict__ Vt,
    unsigned short* __restrict__ AO)
{
    __shared__ __align__(16) float P[32][68];

    const int lane = threadIdx.x;
    const int l15  = lane & 15;
    const int quad = lane >> 4;
    const int h    = blockIdx.y;
    const int q0   = (gridDim.x - 1 - blockIdx.x) * 32;  // big tiles first

    const unsigned short* Qh = Qs + (size_t)h * SEQ * DHEAD;
    const unsigned short* Kh = Ks + (size_t)h * SEQ * DHEAD;
    const unsigned short* Vh = Vt + (size_t)h * DHEAD * SEQ;

    // Q fragments: A-layout A[m=lane&15][k=quad*8+j]
    bf16x8 qf[2][2];
#pragma unroll
    for (int mi = 0; mi < 2; mi++)
#pragma unroll
        for (int kc = 0; kc < 2; kc++)
            qf[mi][kc] = *(const bf16x8*)(Qh + (size_t)(q0 + mi * 16 + l15) * DHEAD + kc * 32 + quad * 8);

    f32x4 o[2][4] = {};
    float mrow[2][4], lrow[2][4];
#pragma unroll
    for (int mi = 0; mi < 2; mi++)
#pragma unroll
        for (int r = 0; r < 4; r++) { mrow[mi][r] = -1e30f; lrow[mi][r] = 0.0f; }

    const int ntiles = (q0 + 95) >> 6;   // cover cols <= q0+31
    for (int tk = 0; tk < ntiles; tk++) {
        const int k0 = tk * 64;

        bf16x8 kf[4][2];
#pragma unroll
        for (int ni = 0; ni < 4; ni++)
#pragma unroll
            for (int kc = 0; kc < 2; kc++)
                kf[ni][kc] = *(const bf16x8*)(Kh + (size_t)(k0 + ni * 16 + l15) * DHEAD + kc * 32 + quad * 8);

        f32x4 sc[2][4] = {};
#pragma unroll
        for (int mi = 0; mi < 2; mi++)
#pragma unroll
            for (int ni = 0; ni < 4; ni++)
#pragma unroll
                for (int kc = 0; kc < 2; kc++)
                    sc[mi][ni] = __builtin_amdgcn_mfma_f32_16x16x32_bf16(
                        qf[mi][kc], kf[ni][kc], sc[mi][ni], 0, 0, 0);

        if (k0 + 63 > q0) {   // diagonal tile: causal mask
#pragma unroll
            for (int mi = 0; mi < 2; mi++)
#pragma unroll
                for (int ni = 0; ni < 4; ni++) {
                    const int col = k0 + ni * 16 + l15;
#pragma unroll
                    for (int r = 0; r < 4; r++) {
                        const int row = q0 + mi * 16 + quad * 4 + r;
                        if (col > row) sc[mi][ni][r] = -1e30f;
                    }
                }
        }

        // online softmax (row state replicated across the quad's 16 lanes)
#pragma unroll
        for (int mi = 0; mi < 2; mi++) {
            float mx[4];
#pragma unroll
            for (int r = 0; r < 4; r++) {
                mx[r] = sc[mi][0][r];
#pragma unroll
                for (int ni = 1; ni < 4; ni++) mx[r] = fmaxf(mx[r], sc[mi][ni][r]);
            }
#pragma unroll
            for (int off = 1; off < 16; off <<= 1)
#pragma unroll
                for (int r = 0; r < 4; r++) mx[r] = fmaxf(mx[r], __shfl_xor(mx[r], off));
            float alpha[4], sum[4];
#pragma unroll
            for (int r = 0; r < 4; r++) {
                float mnew = fmaxf(mrow[mi][r], mx[r]);
                alpha[r] = exp2f(mrow[mi][r] - mnew);
                mrow[mi][r] = mnew;
                sum[r] = 0.0f;
            }
#pragma unroll
            for (int ni = 0; ni < 4; ni++)
#pragma unroll
                for (int r = 0; r < 4; r++) {
                    float p = exp2f(sc[mi][ni][r] - mrow[mi][r]);
                    sc[mi][ni][r] = p;
                    sum[r] += p;
                }
#pragma unroll
            for (int off = 1; off < 16; off <<= 1)
#pragma unroll
                for (int r = 0; r < 4; r++) sum[r] += __shfl_xor(sum[r], off);
#pragma unroll
            for (int r = 0; r < 4; r++) lrow[mi][r] = lrow[mi][r] * alpha[r] + sum[r];
#pragma unroll
            for (int dc = 0; dc < 4; dc++)
#pragma unroll
                for (int r = 0; r < 4; r++) o[mi][dc][r] *= alpha[r];
#pragma unroll
            for (int ni = 0; ni < 4; ni++)
#pragma unroll
                for (int r = 0; r < 4; r++)
                    P[mi * 16 + quad * 4 + r][ni * 16 + l15] = sc[mi][ni][r];
        }
        __syncthreads();

        // P back as A-layout fragments
        bf16x8 pf[2][2];
#pragma unroll
        for (int mi = 0; mi < 2; mi++)
#pragma unroll
            for (int kc = 0; kc < 2; kc++) {
                const float* pr = &P[mi * 16 + l15][kc * 32 + quad * 8];
                f32x4 p0 = *(const f32x4*)(pr);
                f32x4 p1 = *(const f32x4*)(pr + 4);
                union { bf16x8 v; unsigned short u[8]; } pk;
#pragma unroll
                for (int j = 0; j < 4; j++) { pk.u[j] = f2bf(p0[j]); pk.u[4 + j] = f2bf(p1[j]); }
                pf[mi][kc] = pk.v;
            }

        bf16x8 vf[4][2];
#pragma unroll
        for (int dc = 0; dc < 4; dc++)
#pragma unroll
            for (int kc = 0; kc < 2; kc++)
                vf[dc][kc] = *(const bf16x8*)(Vh + (size_t)(dc * 16 + l15) * SEQ + k0 + kc * 32 + quad * 8);

#pragma unroll
        for (int mi = 0; mi < 2; mi++)
#pragma unroll
            for (int dc = 0; dc < 4; dc++)
#pragma unroll
                for (int kc = 0; kc < 2; kc++)
                    o[mi][dc] = __builtin_amdgcn_mfma_f32_16x16x32_bf16(
                        pf[mi][kc], vf[dc][kc], o[mi][dc], 0, 0, 0);
        __syncthreads();   // protect P before next tile overwrites
    }

    // normalize + store to model layout [s][h*64+d], internal bf16
#pragma unroll
    for (int mi = 0; mi < 2; mi++) {
        float inv[4];
#pragma unroll
        for (int r = 0; r < 4; r++) inv[r] = 1.0f / lrow[mi][r];
#pragma unroll
        for (int dc = 0; dc < 4; dc++)
#pragma unroll
            for (int r = 0; r < 4; r++)
                AO[(size_t)(q0 + mi * 16 + quad * 4 + r) * DMODEL + h * DHEAD + dc * 16 + l15]
                    = f2bf(o[mi][dc][r] * inv[r]);
    }
}

// ---------------------------------------------------------------------------
extern "C" void kernel_launch(void* const* d_in, const int* in_sizes, int n_in,
                              void* d_out, int out_size, void* d_ws, size_t ws_size,
                              hipStream_t stream)
{
    (void)in_sizes; (void)n_in; (void)out_size; (void)ws_size;

    const unsigned short* x     = (const unsigned short*)d_in[0]; // [4096][768]
    const unsigned short* W_in  = (const unsigned short*)d_in[1]; // [2304][768]
    const unsigned short* b_in  = (const unsigned short*)d_in[2]; // [2304]
    const unsigned short* W_out = (const unsigned short*)d_in[3]; // [768][768]
    const unsigned short* b_out = (const unsigned short*)d_in[4]; // [768]
    unsigned short* out = (unsigned short*)d_out;                 // [4096][768]

    char* p = (char*)d_ws;
    int* flag = (int*)p; p += 256;                          // dtype flag
    const size_t sz_sd = (size_t)SEQ * DMODEL * 2;          // 6.29 MB
    unsigned short* qs = (unsigned short*)p; p += sz_sd;    // [12][4096][64]
    unsigned short* ks = (unsigned short*)p; p += sz_sd;    // [12][4096][64]
    unsigned short* vs = (unsigned short*)p; p += sz_sd;    // [12][4096][64]
    unsigned short* vt = (unsigned short*)p; p += sz_sd;    // [12][64][4096]
    unsigned short* ao = (unsigned short*)p; p += sz_sd;    // [4096][768]

    // 0) detect external dtype (bf16 vs fp32) from W_in bit patterns
    detect_dtype_kernel<<<1, 256, 0, stream>>>(W_in, flag);
    // 1) qkv projection + head-major scatter (q pre-scaled for base-2 softmax)
    gemm_bt_kernel<0><<<dim3(18, 32), 256, 0, stream>>>(
        x, W_in, b_in, DMODEL, 3 * DMODEL, flag, qs, ks, vs, nullptr);
    // 2) V -> V^T per head
    transpose_v_kernel<<<dim3(64, 12), 256, 0, stream>>>(vs, vt);
    // 3) causal flash attention
    attn_kernel<<<dim3(128, 12), 64, 0, stream>>>(qs, ks, vt, ao);
    // 4) output projection
    gemm_bt_kernel<1><<<dim3(6, 32), 256, 0, stream>>>(
        ao, W_out, b_out, DMODEL, DMODEL, flag, nullptr, nullptr, nullptr, out);
}

// Round 3
// 345.789 us; speedup vs baseline: 1.1495x; 1.1495x over previous
//
#include <hip/hip_runtime.h>
#include <stdint.h>
#include <stddef.h>

// Problem constants
#define SEQ    4096
#define DMODEL 768
#define NHEAD  12
#define DHEAD  64
// (1/sqrt(DHEAD)) * log2(e): fold softmax scale AND base-2 conversion into Q
#define QSCALE 0.18033688011112042f

typedef __attribute__((ext_vector_type(8))) short bf16x8;   // 8 bf16 = 4 VGPRs
typedef __attribute__((ext_vector_type(4))) float f32x4;    // MFMA acc

__device__ __forceinline__ unsigned short f2bf(float f) {
    union { float f; unsigned int u; } v; v.f = f;
    unsigned int r = v.u + 0x7FFFu + ((v.u >> 16) & 1u);   // RNE
    return (unsigned short)(r >> 16);
}
__device__ __forceinline__ float bf2f(unsigned short b) {
    union { float f; unsigned int u; } v; v.u = ((unsigned int)b) << 16;
    return v.f;
}
// 8 consecutive fp32 -> bf16x8 (RNE)
__device__ __forceinline__ bf16x8 ld8f_bf(const float* p) {
    f32x4 lo = *(const f32x4*)p;
    f32x4 hi = *(const f32x4*)(p + 4);
    union { bf16x8 v; unsigned short u[8]; } pk;
#pragma unroll
    for (int j = 0; j < 4; j++) { pk.u[j] = f2bf(lo[j]); pk.u[4 + j] = f2bf(hi[j]); }
    return pk.v;
}

// ---------------------------------------------------------------------------
// GEMM (BT layout): C[M,N] = A[M,K] * B[N,K]^T + bias.  External I/O = fp32.
// 128x128 block, BK=64, 256 threads = 4 waves (2x2), each wave 64x64.
// EPI=0: A,B,bias fp32; scatter into Q(scaled)/K/V head-major bf16 ws.
// EPI=1: A internal bf16; B,bias fp32; output fp32 [M,N].
// ---------------------------------------------------------------------------
template <int EPI>
__global__ __launch_bounds__(256, 2) void gemm_bt_kernel(
    const void* __restrict__ Av,
    const float* __restrict__ B,
    const float* __restrict__ bias,
    int K, int N,
    unsigned short* __restrict__ oq,
    unsigned short* __restrict__ ok,
    unsigned short* __restrict__ ov,
    float* __restrict__ ob)
{
    __shared__ __align__(16) unsigned short As[128 * 72];  // stride 72: conflict-free
    __shared__ __align__(16) unsigned short Bs[128 * 72];

    const int t    = threadIdx.x;
    const int lane = t & 63;
    const int wave = t >> 6;
    const int l15  = lane & 15;
    const int quad = lane >> 4;
    const int wm   = wave >> 1;
    const int wn   = wave & 1;
    const int m0   = blockIdx.y * 128;
    const int n0   = blockIdx.x * 128;

    f32x4 acc[4][4] = {};

    for (int k0 = 0; k0 < K; k0 += 64) {
        bf16x8 ra[4], rb[4];
#pragma unroll
        for (int c = 0; c < 4; c++) {
            int g = c * 256 + t;
            int row = g >> 3, cg = g & 7;
            size_t offa = (size_t)(m0 + row) * K + (k0 + cg * 8);
            size_t offb = (size_t)(n0 + row) * K + (k0 + cg * 8);
            if (EPI == 1) ra[c] = *(const bf16x8*)((const unsigned short*)Av + offa);
            else          ra[c] = ld8f_bf((const float*)Av + offa);
            rb[c] = ld8f_bf(B + offb);
        }
        __syncthreads();   // previous iteration's LDS reads done
#pragma unroll
        for (int c = 0; c < 4; c++) {
            int g = c * 256 + t;
            int row = g >> 3, cg = g & 7;
            *(bf16x8*)(As + row * 72 + cg * 8) = ra[c];
            *(bf16x8*)(Bs + row * 72 + cg * 8) = rb[c];
        }
        __syncthreads();
#pragma unroll
        for (int ki = 0; ki < 2; ki++) {
            bf16x8 af[4], bfr[4];
#pragma unroll
            for (int mi = 0; mi < 4; mi++)
                af[mi] = *(const bf16x8*)(As + (wm * 64 + mi * 16 + l15) * 72 + ki * 32 + quad * 8);
#pragma unroll
            for (int ni = 0; ni < 4; ni++)
                bfr[ni] = *(const bf16x8*)(Bs + (wn * 64 + ni * 16 + l15) * 72 + ki * 32 + quad * 8);
#pragma unroll
            for (int mi = 0; mi < 4; mi++)
#pragma unroll
                for (int ni = 0; ni < 4; ni++)
                    acc[mi][ni] = __builtin_amdgcn_mfma_f32_16x16x32_bf16(
                        af[mi], bfr[ni], acc[mi][ni], 0, 0, 0);
        }
    }

    // Epilogue. C/D layout: col = lane&15, row = quad*4 + reg.
    if (EPI == 0) {
        const int nbase = n0 + wn * 64;            // multiple of 64 -> head-aligned
        const int which = nbase / DMODEL;          // 0=q 1=k 2=v (uniform per wave)
        const int hh    = (nbase % DMODEL) >> 6;   // head (uniform per wave)
        unsigned short* dst = (which == 0) ? oq : (which == 1) ? ok : ov;
        const float scl = (which == 0) ? QSCALE : 1.0f;
#pragma unroll
        for (int ni = 0; ni < 4; ni++) {
            const int d  = ni * 16 + l15;
            const float bv = bias[nbase + d];
#pragma unroll
            for (int mi = 0; mi < 4; mi++) {
                const int mb = m0 + wm * 64 + mi * 16 + quad * 4;
#pragma unroll
                for (int r = 0; r < 4; r++) {
                    float v = (acc[mi][ni][r] + bv) * scl;
                    dst[((size_t)hh * SEQ + (mb + r)) * DHEAD + d] = f2bf(v);
                }
            }
        }
    } else {
#pragma unroll
        for (int ni = 0; ni < 4; ni++) {
            const int n  = n0 + wn * 64 + ni * 16 + l15;
            const float bv = bias[n];
#pragma unroll
            for (int mi = 0; mi < 4; mi++) {
                const int mb = m0 + wm * 64 + mi * 16 + quad * 4;
#pragma unroll
                for (int r = 0; r < 4; r++)
                    ob[(size_t)(mb + r) * N + n] = acc[mi][ni][r] + bv;
            }
        }
    }
}

// ---------------------------------------------------------------------------
// V transpose: V[h][s][d] -> Vt[h][d][s] (internal bf16), 64x64 tiles via LDS.
// ---------------------------------------------------------------------------
__global__ __launch_bounds__(256) void transpose_v_kernel(
    const unsigned short* __restrict__ V, unsigned short* __restrict__ Vt)
{
    __shared__ unsigned short L[64][65];
    const int h  = blockIdx.y;
    const int s0 = blockIdx.x * 64;
    const int t  = threadIdx.x;
#pragma unroll
    for (int it = 0; it < 16; it++) {
        int s = it * 4 + (t >> 6), d = t & 63;
        L[d][s] = V[((size_t)h * SEQ + s0 + s) * DHEAD + d];
    }
    __syncthreads();
#pragma unroll
    for (int it = 0; it < 16; it++) {
        int d = it * 4 + (t >> 6), s = t & 63;
        Vt[((size_t)h * DHEAD + d) * SEQ + s0 + s] = L[d][s];
    }
}

// ---------------------------------------------------------------------------
// Flash attention, causal, S^T formulation. 1 wave / block, 32 Q-rows.
// Computes Sc^T = K·Q^T (C rows = k-cols, C cols = q-rows) so each lane owns
// full softmax rows: in-register 16-way tree + 2 shfl steps. P^T goes to LDS
// as bf16 (packed b64 writes), PV runs as O^T = V^T · P^T.
// Q pre-scaled by SCALE*log2e -> softmax in base 2. No __syncthreads needed.
// ---------------------------------------------------------------------------
__global__ __launch_bounds__(64) void attn_kernel(
    const unsigned short* __restrict__ Qs,
    const unsigned short* __restrict__ Ks,
    const unsigned short* __restrict__ Vt,
    unsigned short* __restrict__ AO)
{
    __shared__ __align__(16) unsigned short P[32 * 72];  // P[q][kcol] bf16

    const int lane = threadIdx.x;
    const int l15  = lane & 15;
    const int quad = lane >> 4;
    const int h    = blockIdx.y;
    const int q0   = (gridDim.x - 1 - blockIdx.x) * 32;  // longest waves first

    const unsigned short* Qh = Qs + (size_t)h * SEQ * DHEAD;
    const unsigned short* Kh = Ks + (size_t)h * SEQ * DHEAD;
    const unsigned short* Vh = Vt + (size_t)h * DHEAD * SEQ;

    // Q as B-operand: lane n=l15 -> q-row, k=quad*8+j -> d
    bf16x8 qf[2][2];
#pragma unroll
    for (int qh = 0; qh < 2; qh++)
#pragma unroll
        for (int kc = 0; kc < 2; kc++)
            qf[qh][kc] = *(const bf16x8*)(Qh + (size_t)(q0 + qh * 16 + l15) * DHEAD + kc * 32 + quad * 8);

    f32x4 o[2][4] = {};            // o[qh][mi]: O^T C-layout, col=q(l15), row=d
    float mq[2] = { -1e30f, -1e30f };
    float lq[2] = { 0.0f, 0.0f };  // per-lane row state (replicated across quads)

    const int ntiles = (q0 + 95) >> 6;
    for (int tk = 0; tk < ntiles; tk++) {
        const int k0 = tk * 64;

        // K as A-operand: lane m=l15 -> kcol, k=quad*8+j -> d
        bf16x8 kf[4][2];
#pragma unroll
        for (int ni = 0; ni < 4; ni++)
#pragma unroll
            for (int kc = 0; kc < 2; kc++)
                kf[ni][kc] = *(const bf16x8*)(Kh + (size_t)(k0 + ni * 16 + l15) * DHEAD + kc * 32 + quad * 8);

        // Sc^T[ni][qh]: C row = kcol (quad*4+r within tile), col = q (l15)
        f32x4 sc[4][2] = {};
#pragma unroll
        for (int ni = 0; ni < 4; ni++)
#pragma unroll
            for (int qh = 0; qh < 2; qh++)
#pragma unroll
                for (int kc = 0; kc < 2; kc++)
                    sc[ni][qh] = __builtin_amdgcn_mfma_f32_16x16x32_bf16(
                        kf[ni][kc], qf[qh][kc], sc[ni][qh], 0, 0, 0);

        // V^T as A-operand (issued now; latency hides under softmax):
        // lane m=l15 -> d, k=quad*8+j -> kcol
        bf16x8 vf[4][2];
#pragma unroll
        for (int mi = 0; mi < 4; mi++)
#pragma unroll
            for (int kc = 0; kc < 2; kc++)
                vf[mi][kc] = *(const bf16x8*)(Vh + (size_t)(mi * 16 + l15) * SEQ + k0 + kc * 32 + quad * 8);

        if (k0 + 63 > q0) {   // diagonal tiles: mask kcol > q
#pragma unroll
            for (int ni = 0; ni < 4; ni++)
#pragma unroll
                for (int qh = 0; qh < 2; qh++) {
                    const int q = q0 + qh * 16 + l15;
#pragma unroll
                    for (int r = 0; r < 4; r++) {
                        const int kcol = k0 + ni * 16 + quad * 4 + r;
                        if (kcol > q) sc[ni][qh][r] = -1e30f;
                    }
                }
        }

        // Online softmax: each lane reduces its 16 regs, then 2 cross-quad shfl
#pragma unroll
        for (int qh = 0; qh < 2; qh++) {
            float mx = sc[0][qh][0];
#pragma unroll
            for (int ni = 0; ni < 4; ni++)
#pragma unroll
                for (int r = 0; r < 4; r++) mx = fmaxf(mx, sc[ni][qh][r]);
            mx = fmaxf(mx, __shfl_xor(mx, 16));
            mx = fmaxf(mx, __shfl_xor(mx, 32));
            const float mnew  = fmaxf(mq[qh], mx);
            const float alpha = exp2f(mq[qh] - mnew);
            mq[qh] = mnew;
            float sum = 0.0f;
#pragma unroll
            for (int ni = 0; ni < 4; ni++)
#pragma unroll
                for (int r = 0; r < 4; r++) {
                    float p = exp2f(sc[ni][qh][r] - mnew);
                    sc[ni][qh][r] = p;
                    sum += p;
                }
            sum += __shfl_xor(sum, 16);
            sum += __shfl_xor(sum, 32);
            lq[qh] = lq[qh] * alpha + sum;
#pragma unroll
            for (int mi = 0; mi < 4; mi++)
#pragma unroll
                for (int r = 0; r < 4; r++) o[qh][mi][r] *= alpha;
            // P[q][kcol] bf16: 4 consecutive kcols per reg-group -> packed b64
#pragma unroll
            for (int ni = 0; ni < 4; ni++) {
                union { unsigned short u[4]; uint2 v; } pk;
#pragma unroll
                for (int r = 0; r < 4; r++) pk.u[r] = f2bf(sc[ni][qh][r]);
                *(uint2*)(P + (qh * 16 + l15) * 72 + ni * 16 + quad * 4) = pk.v;
            }
        }

        // P^T as B-operand: lane n=l15 -> q, k=quad*8+j -> kcol (contiguous)
        bf16x8 pf[2][2];
#pragma unroll
        for (int qh = 0; qh < 2; qh++)
#pragma unroll
            for (int kc = 0; kc < 2; kc++)
                pf[qh][kc] = *(const bf16x8*)(P + (qh * 16 + l15) * 72 + kc * 32 + quad * 8);

#pragma unroll
        for (int qh = 0; qh < 2; qh++)
#pragma unroll
            for (int mi = 0; mi < 4; mi++)
#pragma unroll
                for (int kc = 0; kc < 2; kc++)
                    o[qh][mi] = __builtin_amdgcn_mfma_f32_16x16x32_bf16(
                        vf[mi][kc], pf[qh][kc], o[qh][mi], 0, 0, 0);
    }

    // normalize + store: lane's column q = q0+qh*16+l15, rows d = mi*16+quad*4+r
#pragma unroll
    for (int qh = 0; qh < 2; qh++) {
        const float inv = 1.0f / lq[qh];
        const size_t rowoff = (size_t)(q0 + qh * 16 + l15) * DMODEL + h * DHEAD;
#pragma unroll
        for (int mi = 0; mi < 4; mi++) {
            union { unsigned short u[4]; uint2 v; } pk;
#pragma unroll
            for (int r = 0; r < 4; r++) pk.u[r] = f2bf(o[qh][mi][r] * inv);
            *(uint2*)(AO + rowoff + mi * 16 + quad * 4) = pk.v;
        }
    }
}

// ---------------------------------------------------------------------------
extern "C" void kernel_launch(void* const* d_in, const int* in_sizes, int n_in,
                              void* d_out, int out_size, void* d_ws, size_t ws_size,
                              hipStream_t stream)
{
    (void)in_sizes; (void)n_in; (void)out_size; (void)ws_size;

    const float* x     = (const float*)d_in[0]; // [4096][768] fp32
    const float* W_in  = (const float*)d_in[1]; // [2304][768] fp32
    const float* b_in  = (const float*)d_in[2]; // [2304] fp32
    const float* W_out = (const float*)d_in[3]; // [768][768] fp32
    const float* b_out = (const float*)d_in[4]; // [768] fp32
    float* out = (float*)d_out;                 // [4096][768] fp32

    char* p = (char*)d_ws;
    const size_t sz_sd = (size_t)SEQ * DMODEL * 2;          // 6.29 MB
    unsigned short* qs = (unsigned short*)p; p += sz_sd;    // [12][4096][64]
    unsigned short* ks = (unsigned short*)p; p += sz_sd;    // [12][4096][64]
    unsigned short* vs = (unsigned short*)p; p += sz_sd;    // [12][4096][64]
    unsigned short* vt = (unsigned short*)p; p += sz_sd;    // [12][64][4096]
    unsigned short* ao = (unsigned short*)p; p += sz_sd;    // [4096][768]

    // 1) qkv projection + head-major scatter (q pre-scaled for base-2 softmax)
    gemm_bt_kernel<0><<<dim3(18, 32), 256, 0, stream>>>(
        (const void*)x, W_in, b_in, DMODEL, 3 * DMODEL, qs, ks, vs, nullptr);
    // 2) V -> V^T per head
    transpose_v_kernel<<<dim3(64, 12), 256, 0, stream>>>(vs, vt);
    // 3) causal flash attention (S^T formulation)
    attn_kernel<<<dim3(128, 12), 64, 0, stream>>>(qs, ks, vt, ao);
    // 4) output projection
    gemm_bt_kernel<1><<<dim3(6, 32), 256, 0, stream>>>(
        (const void*)ao, W_out, b_out, DMODEL, DMODEL, nullptr, nullptr, nullptr, out);
}

// Round 4
// 302.929 us; speedup vs baseline: 1.3121x; 1.1415x over previous
//
#include <hip/hip_runtime.h>
#include <stdint.h>
#include <stddef.h>

// Problem constants
#define SEQ    4096
#define DMODEL 768
#define NHEAD  12
#define DHEAD  64
// (1/sqrt(DHEAD)) * log2(e): fold softmax scale AND base-2 conversion into Q
#define QSCALE 0.18033688011112042f

typedef __attribute__((ext_vector_type(8))) short bf16x8;   // 8 bf16 = 4 VGPRs
typedef __attribute__((ext_vector_type(4))) float f32x4;    // MFMA acc

__device__ __forceinline__ unsigned short f2bf(float f) {
    union { float f; unsigned int u; } v; v.f = f;
    unsigned int r = v.u + 0x7FFFu + ((v.u >> 16) & 1u);   // RNE
    return (unsigned short)(r >> 16);
}
// 8 consecutive fp32 -> bf16x8 (RNE)
__device__ __forceinline__ bf16x8 ld8f_bf(const float* p) {
    f32x4 lo = *(const f32x4*)p;
    f32x4 hi = *(const f32x4*)(p + 4);
    union { bf16x8 v; unsigned short u[8]; } pk;
#pragma unroll
    for (int j = 0; j < 4; j++) { pk.u[j] = f2bf(lo[j]); pk.u[4 + j] = f2bf(hi[j]); }
    return pk.v;
}

// ---------------------------------------------------------------------------
// GEMM (BT layout): C[M,N] = A[M,K] * B[N,K]^T + bias.  External I/O = fp32.
// 128x128 block, BK=64, 256 threads = 4 waves (2x2), each wave 64x64.
// EPI=0: A,B,bias fp32; scatter into Q(scaled)/K head-major bf16 and V
//        directly TRANSPOSED (Vt[h][d][s]) -- transpose kernel folded in.
// EPI=1: A internal bf16; B,bias fp32; output fp32 [M,N].
// ---------------------------------------------------------------------------
template <int EPI>
__global__ __launch_bounds__(256, 2) void gemm_bt_kernel(
    const void* __restrict__ Av,
    const float* __restrict__ B,
    const float* __restrict__ bias,
    int K, int N,
    unsigned short* __restrict__ oq,
    unsigned short* __restrict__ ok,
    unsigned short* __restrict__ ovt,
    float* __restrict__ ob)
{
    __shared__ __align__(16) unsigned short As[128 * 72];  // stride 72: conflict-free
    __shared__ __align__(16) unsigned short Bs[128 * 72];

    const int t    = threadIdx.x;
    const int lane = t & 63;
    const int wave = t >> 6;
    const int l15  = lane & 15;
    const int quad = lane >> 4;
    const int wm   = wave >> 1;
    const int wn   = wave & 1;
    const int m0   = blockIdx.y * 128;
    const int n0   = blockIdx.x * 128;

    f32x4 acc[4][4] = {};

    for (int k0 = 0; k0 < K; k0 += 64) {
        bf16x8 ra[4], rb[4];
#pragma unroll
        for (int c = 0; c < 4; c++) {
            int g = c * 256 + t;
            int row = g >> 3, cg = g & 7;
            size_t offa = (size_t)(m0 + row) * K + (k0 + cg * 8);
            size_t offb = (size_t)(n0 + row) * K + (k0 + cg * 8);
            if (EPI == 1) ra[c] = *(const bf16x8*)((const unsigned short*)Av + offa);
            else          ra[c] = ld8f_bf((const float*)Av + offa);
            rb[c] = ld8f_bf(B + offb);
        }
        __syncthreads();   // previous iteration's LDS reads done
#pragma unroll
        for (int c = 0; c < 4; c++) {
            int g = c * 256 + t;
            int row = g >> 3, cg = g & 7;
            *(bf16x8*)(As + row * 72 + cg * 8) = ra[c];
            *(bf16x8*)(Bs + row * 72 + cg * 8) = rb[c];
        }
        __syncthreads();
#pragma unroll
        for (int ki = 0; ki < 2; ki++) {
            bf16x8 af[4], bfr[4];
#pragma unroll
            for (int mi = 0; mi < 4; mi++)
                af[mi] = *(const bf16x8*)(As + (wm * 64 + mi * 16 + l15) * 72 + ki * 32 + quad * 8);
#pragma unroll
            for (int ni = 0; ni < 4; ni++)
                bfr[ni] = *(const bf16x8*)(Bs + (wn * 64 + ni * 16 + l15) * 72 + ki * 32 + quad * 8);
#pragma unroll
            for (int mi = 0; mi < 4; mi++)
#pragma unroll
                for (int ni = 0; ni < 4; ni++)
                    acc[mi][ni] = __builtin_amdgcn_mfma_f32_16x16x32_bf16(
                        af[mi], bfr[ni], acc[mi][ni], 0, 0, 0);
        }
    }

    // Epilogue. C/D layout: col = lane&15, row = quad*4 + reg.
    if (EPI == 0) {
        const int nbase = n0 + wn * 64;            // multiple of 64 -> head-aligned
        const int which = nbase / DMODEL;          // 0=q 1=k 2=v (uniform per wave)
        const int hh    = (nbase % DMODEL) >> 6;   // head (uniform per wave)
        if (which < 2) {
            unsigned short* dst = (which == 0) ? oq : ok;
            const float scl = (which == 0) ? QSCALE : 1.0f;
#pragma unroll
            for (int ni = 0; ni < 4; ni++) {
                const int d  = ni * 16 + l15;
                const float bv = bias[nbase + d];
#pragma unroll
                for (int mi = 0; mi < 4; mi++) {
                    const int mb = m0 + wm * 64 + mi * 16 + quad * 4;
#pragma unroll
                    for (int r = 0; r < 4; r++) {
                        float v = (acc[mi][ni][r] + bv) * scl;
                        dst[((size_t)hh * SEQ + (mb + r)) * DHEAD + d] = f2bf(v);
                    }
                }
            }
        } else {
            // V: write transposed Vt[h][d][s]; s-base mb is 4-aligned -> uint2
#pragma unroll
            for (int ni = 0; ni < 4; ni++) {
                const int d  = ni * 16 + l15;
                const float bv = bias[nbase + d];
#pragma unroll
                for (int mi = 0; mi < 4; mi++) {
                    const int mb = m0 + wm * 64 + mi * 16 + quad * 4;
                    union { unsigned short u[4]; uint2 v; } pk;
#pragma unroll
                    for (int r = 0; r < 4; r++) pk.u[r] = f2bf(acc[mi][ni][r] + bv);
                    *(uint2*)(ovt + ((size_t)hh * DHEAD + d) * SEQ + mb) = pk.v;
                }
            }
        }
    } else {
#pragma unroll
        for (int ni = 0; ni < 4; ni++) {
            const int n  = n0 + wn * 64 + ni * 16 + l15;
            const float bv = bias[n];
#pragma unroll
            for (int mi = 0; mi < 4; mi++) {
                const int mb = m0 + wm * 64 + mi * 16 + quad * 4;
#pragma unroll
                for (int r = 0; r < 4; r++)
                    ob[(size_t)(mb + r) * N + n] = acc[mi][ni][r] + bv;
            }
        }
    }
}

// ---------------------------------------------------------------------------
// Flash attention, causal, S^T formulation, INTRA-BLOCK SPLIT-K.
// Block = 4 waves on the same 32 q-rows; wave w takes k-tiles w, w+4, ...
// each with private (m, l, O^T) online-softmax state. Merge via LDS:
//   O = sum_w exp2(m_w - m_max) * O_w / sum_w exp2(m_w - m_max) * l_w.
// P-staging LDS (loop phase) is overlap-unioned with partial-O LDS (merge
// phase); barrier #1 separates the phases, barrier #2 guards the merge reads.
// ---------------------------------------------------------------------------
__global__ __launch_bounds__(256) void attn_kernel(
    const unsigned short* __restrict__ Qs,
    const unsigned short* __restrict__ Ks,
    const unsigned short* __restrict__ Vt,
    unsigned short* __restrict__ AO)
{
    // bytes 0..18432: P staging, 4 waves x (32 x 72) u16
    // bytes 0..36864: O partials, [4 waves][64 d][36 q] f32 (q-stride 36: 2-way only)
    // bytes 36864..37888: m [4][32] f32 then l [4][32] f32
    __shared__ __align__(16) char LB[37888];

    const int t    = threadIdx.x;
    const int lane = t & 63;
    const int w    = t >> 6;      // k-split wave id
    const int l15  = lane & 15;
    const int quad = lane >> 4;
    const int h    = blockIdx.y;
    const int q0   = (gridDim.x - 1 - blockIdx.x) * 32;  // longest blocks first

    unsigned short* Pw  = (unsigned short*)LB + w * 32 * 72;
    float*          Old = (float*)LB;
    float*          Mld = (float*)(LB + 36864);
    float*          Lld = Mld + 4 * 32;

    const unsigned short* Qh = Qs + (size_t)h * SEQ * DHEAD;
    const unsigned short* Kh = Ks + (size_t)h * SEQ * DHEAD;
    const unsigned short* Vh = Vt + (size_t)h * DHEAD * SEQ;

    // Q as B-operand: lane n=l15 -> q-row, k=quad*8+j -> d
    bf16x8 qf[2][2];
#pragma unroll
    for (int qh = 0; qh < 2; qh++)
#pragma unroll
        for (int kc = 0; kc < 2; kc++)
            qf[qh][kc] = *(const bf16x8*)(Qh + (size_t)(q0 + qh * 16 + l15) * DHEAD + kc * 32 + quad * 8);

    f32x4 o[2][4] = {};            // O^T partial: col=q(l15), row=d
    float mq[2] = { -1e30f, -1e30f };
    float lq[2] = { 0.0f, 0.0f };

    const int ntiles = (q0 + 95) >> 6;
    for (int tk = w; tk < ntiles; tk += 4) {
        const int k0 = tk * 64;

        // K as A-operand: lane m=l15 -> kcol, k=quad*8+j -> d
        bf16x8 kf[4][2];
#pragma unroll
        for (int ni = 0; ni < 4; ni++)
#pragma unroll
            for (int kc = 0; kc < 2; kc++)
                kf[ni][kc] = *(const bf16x8*)(Kh + (size_t)(k0 + ni * 16 + l15) * DHEAD + kc * 32 + quad * 8);

        // Sc^T[ni][qh]: C row = kcol (quad*4+r), col = q (l15)
        f32x4 sc[4][2] = {};
#pragma unroll
        for (int ni = 0; ni < 4; ni++)
#pragma unroll
            for (int qh = 0; qh < 2; qh++)
#pragma unroll
                for (int kc = 0; kc < 2; kc++)
                    sc[ni][qh] = __builtin_amdgcn_mfma_f32_16x16x32_bf16(
                        kf[ni][kc], qf[qh][kc], sc[ni][qh], 0, 0, 0);

        // V^T as A-operand, issued early so latency hides under softmax
        bf16x8 vf[4][2];
#pragma unroll
        for (int mi = 0; mi < 4; mi++)
#pragma unroll
            for (int kc = 0; kc < 2; kc++)
                vf[mi][kc] = *(const bf16x8*)(Vh + (size_t)(mi * 16 + l15) * SEQ + k0 + kc * 32 + quad * 8);

        if (k0 + 63 > q0) {   // diagonal tiles: mask kcol > q
#pragma unroll
            for (int ni = 0; ni < 4; ni++)
#pragma unroll
                for (int qh = 0; qh < 2; qh++) {
                    const int q = q0 + qh * 16 + l15;
#pragma unroll
                    for (int r = 0; r < 4; r++) {
                        const int kcol = k0 + ni * 16 + quad * 4 + r;
                        if (kcol > q) sc[ni][qh][r] = -1e30f;
                    }
                }
        }

        // Online softmax: 16-reg in-register tree + 2 cross-quad shfl
#pragma unroll
        for (int qh = 0; qh < 2; qh++) {
            float mx = sc[0][qh][0];
#pragma unroll
            for (int ni = 0; ni < 4; ni++)
#pragma unroll
                for (int r = 0; r < 4; r++) mx = fmaxf(mx, sc[ni][qh][r]);
            mx = fmaxf(mx, __shfl_xor(mx, 16));
            mx = fmaxf(mx, __shfl_xor(mx, 32));
            const float mnew  = fmaxf(mq[qh], mx);
            const float alpha = exp2f(mq[qh] - mnew);
            mq[qh] = mnew;
            float sum = 0.0f;
#pragma unroll
            for (int ni = 0; ni < 4; ni++)
#pragma unroll
                for (int r = 0; r < 4; r++) {
                    float p = exp2f(sc[ni][qh][r] - mnew);
                    sc[ni][qh][r] = p;
                    sum += p;
                }
            sum += __shfl_xor(sum, 16);
            sum += __shfl_xor(sum, 32);
            lq[qh] = lq[qh] * alpha + sum;
#pragma unroll
            for (int mi = 0; mi < 4; mi++)
#pragma unroll
                for (int r = 0; r < 4; r++) o[qh][mi][r] *= alpha;
            // P[q][kcol] bf16, packed b64 writes
#pragma unroll
            for (int ni = 0; ni < 4; ni++) {
                union { unsigned short u[4]; uint2 v; } pk;
#pragma unroll
                for (int r = 0; r < 4; r++) pk.u[r] = f2bf(sc[ni][qh][r]);
                *(uint2*)(Pw + (qh * 16 + l15) * 72 + ni * 16 + quad * 4) = pk.v;
            }
        }

        // P^T as B-operand: lane n=l15 -> q, k=quad*8+j -> kcol
        bf16x8 pf[2][2];
#pragma unroll
        for (int qh = 0; qh < 2; qh++)
#pragma unroll
            for (int kc = 0; kc < 2; kc++)
                pf[qh][kc] = *(const bf16x8*)(Pw + (qh * 16 + l15) * 72 + kc * 32 + quad * 8);

#pragma unroll
        for (int qh = 0; qh < 2; qh++)
#pragma unroll
            for (int mi = 0; mi < 4; mi++)
#pragma unroll
                for (int kc = 0; kc < 2; kc++)
                    o[qh][mi] = __builtin_amdgcn_mfma_f32_16x16x32_bf16(
                        vf[mi][kc], pf[qh][kc], o[qh][mi], 0, 0, 0);
    }

    __syncthreads();   // all waves done with P region (O region overlays it)

    // dump partials: O^T[w][d][q], m/l[w][q]
#pragma unroll
    for (int qh = 0; qh < 2; qh++)
#pragma unroll
        for (int mi = 0; mi < 4; mi++)
#pragma unroll
            for (int r = 0; r < 4; r++)
                Old[(w * 64 + mi * 16 + quad * 4 + r) * 36 + qh * 16 + l15] = o[qh][mi][r];
    if (quad == 0) {
#pragma unroll
        for (int qh = 0; qh < 2; qh++) {
            Mld[w * 32 + qh * 16 + l15] = mq[qh];
            Lld[w * 32 + qh * 16 + l15] = lq[qh];
        }
    }
    __syncthreads();

    // merge: wave w owns d-rows [w*16, w*16+16)
#pragma unroll
    for (int qh = 0; qh < 2; qh++) {
        const int q = qh * 16 + l15;
        float m4[4], l4[4];
#pragma unroll
        for (int ws = 0; ws < 4; ws++) { m4[ws] = Mld[ws * 32 + q]; l4[ws] = Lld[ws * 32 + q]; }
        const float mmax = fmaxf(fmaxf(m4[0], m4[1]), fmaxf(m4[2], m4[3]));
        float aw[4], ltot = 0.0f;
#pragma unroll
        for (int ws = 0; ws < 4; ws++) { aw[ws] = exp2f(m4[ws] - mmax); ltot += aw[ws] * l4[ws]; }
        const float inv = 1.0f / ltot;
        union { unsigned short u[4]; uint2 v; } pk;
#pragma unroll
        for (int r = 0; r < 4; r++) {
            const int d = w * 16 + quad * 4 + r;
            float a = 0.0f;
#pragma unroll
            for (int ws = 0; ws < 4; ws++) a += aw[ws] * Old[(ws * 64 + d) * 36 + q];
            pk.u[r] = f2bf(a * inv);
        }
        *(uint2*)(AO + (size_t)(q0 + q) * DMODEL + h * DHEAD + w * 16 + quad * 4) = pk.v;
    }
}

// ---------------------------------------------------------------------------
extern "C" void kernel_launch(void* const* d_in, const int* in_sizes, int n_in,
                              void* d_out, int out_size, void* d_ws, size_t ws_size,
                              hipStream_t stream)
{
    (void)in_sizes; (void)n_in; (void)out_size; (void)ws_size;

    const float* x     = (const float*)d_in[0]; // [4096][768] fp32
    const float* W_in  = (const float*)d_in[1]; // [2304][768] fp32
    const float* b_in  = (const float*)d_in[2]; // [2304] fp32
    const float* W_out = (const float*)d_in[3]; // [768][768] fp32
    const float* b_out = (const float*)d_in[4]; // [768] fp32
    float* out = (float*)d_out;                 // [4096][768] fp32

    char* p = (char*)d_ws;
    const size_t sz_sd = (size_t)SEQ * DMODEL * 2;          // 6.29 MB
    unsigned short* qs = (unsigned short*)p; p += sz_sd;    // [12][4096][64]
    unsigned short* ks = (unsigned short*)p; p += sz_sd;    // [12][4096][64]
    unsigned short* vt = (unsigned short*)p; p += sz_sd;    // [12][64][4096]
    unsigned short* ao = (unsigned short*)p; p += sz_sd;    // [4096][768]

    // 1) qkv projection; Q scaled, V written pre-transposed
    gemm_bt_kernel<0><<<dim3(18, 32), 256, 0, stream>>>(
        (const void*)x, W_in, b_in, DMODEL, 3 * DMODEL, qs, ks, vt, nullptr);
    // 2) causal flash attention (S^T, intra-block split-K over 4 waves)
    attn_kernel<<<dim3(128, 12), 256, 0, stream>>>(qs, ks, vt, ao);
    // 3) output projection
    gemm_bt_kernel<1><<<dim3(6, 32), 256, 0, stream>>>(
        (const void*)ao, W_out, b_out, DMODEL, DMODEL, nullptr, nullptr, nullptr, out);
}

// Round 5
// 273.394 us; speedup vs baseline: 1.4539x; 1.1080x over previous
//
#include <hip/hip_runtime.h>
#include <stdint.h>
#include <stddef.h>

// Problem constants
#define SEQ    4096
#define DMODEL 768
#define NHEAD  12
#define DHEAD  64
// (1/sqrt(DHEAD)) * log2(e): fold softmax scale AND base-2 conversion into Q
#define QSCALE 0.18033688011112042f

typedef __attribute__((ext_vector_type(8))) short bf16x8;   // 8 bf16 = 4 VGPRs
typedef __attribute__((ext_vector_type(4))) float f32x4;    // MFMA acc

__device__ __forceinline__ unsigned short f2bf(float f) {
    union { float f; unsigned int u; } v; v.f = f;
    unsigned int r = v.u + 0x7FFFu + ((v.u >> 16) & 1u);   // RNE
    return (unsigned short)(r >> 16);
}
// 8 consecutive fp32 -> bf16x8 (RNE)
__device__ __forceinline__ bf16x8 ld8f_bf(const float* p) {
    f32x4 lo = *(const f32x4*)p;
    f32x4 hi = *(const f32x4*)(p + 4);
    union { bf16x8 v; unsigned short u[8]; } pk;
#pragma unroll
    for (int j = 0; j < 4; j++) { pk.u[j] = f2bf(lo[j]); pk.u[4 + j] = f2bf(hi[j]); }
    return pk.v;
}

// ---------------------------------------------------------------------------
// GEMM (BT layout): C[M,N] = A[M,K] * B[N,K]^T + bias.  External I/O = fp32.
// 128x128 block, BK=64, 256 threads = 4 waves (2x2), each wave 64x64.
// EPI=0: A,B,bias fp32; scatter into Q(scaled)/K head-major bf16 and V
//        directly TRANSPOSED (Vt[h][d][s]).
// EPI=1: A internal bf16; B,bias fp32; output fp32 [M,N].
// ---------------------------------------------------------------------------
template <int EPI>
__global__ __launch_bounds__(256, 2) void gemm_bt_kernel(
    const void* __restrict__ Av,
    const float* __restrict__ B,
    const float* __restrict__ bias,
    int K, int N,
    unsigned short* __restrict__ oq,
    unsigned short* __restrict__ ok,
    unsigned short* __restrict__ ovt,
    float* __restrict__ ob)
{
    __shared__ __align__(16) unsigned short As[128 * 72];  // stride 72: conflict-free
    __shared__ __align__(16) unsigned short Bs[128 * 72];

    const int t    = threadIdx.x;
    const int lane = t & 63;
    const int wave = t >> 6;
    const int l15  = lane & 15;
    const int quad = lane >> 4;
    const int wm   = wave >> 1;
    const int wn   = wave & 1;
    const int m0   = blockIdx.y * 128;
    const int n0   = blockIdx.x * 128;

    f32x4 acc[4][4] = {};

    for (int k0 = 0; k0 < K; k0 += 64) {
        bf16x8 ra[4], rb[4];
#pragma unroll
        for (int c = 0; c < 4; c++) {
            int g = c * 256 + t;
            int row = g >> 3, cg = g & 7;
            size_t offa = (size_t)(m0 + row) * K + (k0 + cg * 8);
            size_t offb = (size_t)(n0 + row) * K + (k0 + cg * 8);
            if (EPI == 1) ra[c] = *(const bf16x8*)((const unsigned short*)Av + offa);
            else          ra[c] = ld8f_bf((const float*)Av + offa);
            rb[c] = ld8f_bf(B + offb);
        }
        __syncthreads();   // previous iteration's LDS reads done
#pragma unroll
        for (int c = 0; c < 4; c++) {
            int g = c * 256 + t;
            int row = g >> 3, cg = g & 7;
            *(bf16x8*)(As + row * 72 + cg * 8) = ra[c];
            *(bf16x8*)(Bs + row * 72 + cg * 8) = rb[c];
        }
        __syncthreads();
#pragma unroll
        for (int ki = 0; ki < 2; ki++) {
            bf16x8 af[4], bfr[4];
#pragma unroll
            for (int mi = 0; mi < 4; mi++)
                af[mi] = *(const bf16x8*)(As + (wm * 64 + mi * 16 + l15) * 72 + ki * 32 + quad * 8);
#pragma unroll
            for (int ni = 0; ni < 4; ni++)
                bfr[ni] = *(const bf16x8*)(Bs + (wn * 64 + ni * 16 + l15) * 72 + ki * 32 + quad * 8);
#pragma unroll
            for (int mi = 0; mi < 4; mi++)
#pragma unroll
                for (int ni = 0; ni < 4; ni++)
                    acc[mi][ni] = __builtin_amdgcn_mfma_f32_16x16x32_bf16(
                        af[mi], bfr[ni], acc[mi][ni], 0, 0, 0);
        }
    }

    // Epilogue. C/D layout: col = lane&15, row = quad*4 + reg.
    if (EPI == 0) {
        const int nbase = n0 + wn * 64;            // multiple of 64 -> head-aligned
        const int which = nbase / DMODEL;          // 0=q 1=k 2=v (uniform per wave)
        const int hh    = (nbase % DMODEL) >> 6;   // head (uniform per wave)
        if (which < 2) {
            unsigned short* dst = (which == 0) ? oq : ok;
            const float scl = (which == 0) ? QSCALE : 1.0f;
#pragma unroll
            for (int ni = 0; ni < 4; ni++) {
                const int d  = ni * 16 + l15;
                const float bv = bias[nbase + d];
#pragma unroll
                for (int mi = 0; mi < 4; mi++) {
                    const int mb = m0 + wm * 64 + mi * 16 + quad * 4;
#pragma unroll
                    for (int r = 0; r < 4; r++) {
                        float v = (acc[mi][ni][r] + bv) * scl;
                        dst[((size_t)hh * SEQ + (mb + r)) * DHEAD + d] = f2bf(v);
                    }
                }
            }
        } else {
            // V: write transposed Vt[h][d][s]; s-base mb is 4-aligned -> uint2
#pragma unroll
            for (int ni = 0; ni < 4; ni++) {
                const int d  = ni * 16 + l15;
                const float bv = bias[nbase + d];
#pragma unroll
                for (int mi = 0; mi < 4; mi++) {
                    const int mb = m0 + wm * 64 + mi * 16 + quad * 4;
                    union { unsigned short u[4]; uint2 v; } pk;
#pragma unroll
                    for (int r = 0; r < 4; r++) pk.u[r] = f2bf(acc[mi][ni][r] + bv);
                    *(uint2*)(ovt + ((size_t)hh * DHEAD + d) * SEQ + mb) = pk.v;
                }
            }
        }
    } else {
#pragma unroll
        for (int ni = 0; ni < 4; ni++) {
            const int n  = n0 + wn * 64 + ni * 16 + l15;
            const float bv = bias[n];
#pragma unroll
            for (int mi = 0; mi < 4; mi++) {
                const int mb = m0 + wm * 64 + mi * 16 + quad * 4;
#pragma unroll
                for (int r = 0; r < 4; r++)
                    ob[(size_t)(mb + r) * N + n] = acc[mi][ni][r] + bv;
            }
        }
    }
}

// ---------------------------------------------------------------------------
// Flash attention, causal, S^T formulation, intra-block split-K (4 waves),
// PAIRED q-tiles for load balance: block px handles q-tiles (127-px) then px,
// whose tile counts sum to a constant ~66 -> all 768 blocks take equal time.
// K loads are software-pipelined one tile ahead (prefetch into kfn after QK).
// ---------------------------------------------------------------------------
__global__ __launch_bounds__(256) void attn_kernel(
    const unsigned short* __restrict__ Qs,
    const unsigned short* __restrict__ Ks,
    const unsigned short* __restrict__ Vt,
    unsigned short* __restrict__ AO)
{
    // bytes 0..18432: P staging, 4 waves x (32 x 72) u16
    // bytes 0..36864: O partials, [4 waves][64 d][36 q] f32 (merge phase)
    // bytes 36864..37888: m [4][32] f32 then l [4][32] f32
    __shared__ __align__(16) char LB[37888];

    const int t    = threadIdx.x;
    const int lane = t & 63;
    const int w    = t >> 6;      // k-split wave id
    const int l15  = lane & 15;
    const int quad = lane >> 4;
    const int h    = blockIdx.y;
    const int px   = blockIdx.x;  // 0..63

    unsigned short* Pw  = (unsigned short*)LB + w * 32 * 72;
    float*          Old = (float*)LB;
    float*          Mld = (float*)(LB + 36864);
    float*          Lld = Mld + 4 * 32;

    const unsigned short* Qh = Qs + (size_t)h * SEQ * DHEAD;
    const unsigned short* Kh = Ks + (size_t)h * SEQ * DHEAD;
    const unsigned short* Vh = Vt + (size_t)h * DHEAD * SEQ;

#pragma unroll 1
    for (int phase = 0; phase < 2; phase++) {
        const int q0 = (phase == 0 ? (127 - px) : px) * 32;

        // Q as B-operand: lane n=l15 -> q-row, k=quad*8+j -> d
        bf16x8 qf[2][2];
#pragma unroll
        for (int qh = 0; qh < 2; qh++)
#pragma unroll
            for (int kc = 0; kc < 2; kc++)
                qf[qh][kc] = *(const bf16x8*)(Qh + (size_t)(q0 + qh * 16 + l15) * DHEAD + kc * 32 + quad * 8);

        f32x4 o[2][4] = {};            // O^T partial: col=q(l15), row=d
        float mq[2] = { -1e30f, -1e30f };
        float lq[2] = { 0.0f, 0.0f };

        const int ntiles = (q0 + 95) >> 6;

        // K prefetch: A-operand, lane m=l15 -> kcol, k=quad*8+j -> d
        bf16x8 kfn[4][2];
        if (w < ntiles) {
            const int k0p = w * 64;
#pragma unroll
            for (int ni = 0; ni < 4; ni++)
#pragma unroll
                for (int kc = 0; kc < 2; kc++)
                    kfn[ni][kc] = *(const bf16x8*)(Kh + (size_t)(k0p + ni * 16 + l15) * DHEAD + kc * 32 + quad * 8);
        }

        for (int tk = w; tk < ntiles; tk += 4) {
            const int k0 = tk * 64;

            // Sc^T[ni][qh]: C row = kcol (quad*4+r), col = q (l15)
            f32x4 sc[4][2] = {};
#pragma unroll
            for (int ni = 0; ni < 4; ni++)
#pragma unroll
                for (int qh = 0; qh < 2; qh++)
#pragma unroll
                    for (int kc = 0; kc < 2; kc++)
                        sc[ni][qh] = __builtin_amdgcn_mfma_f32_16x16x32_bf16(
                            kfn[ni][kc], qf[qh][kc], sc[ni][qh], 0, 0, 0);

            // V^T as A-operand for this tile (consumed after softmax)
            bf16x8 vf[4][2];
#pragma unroll
            for (int mi = 0; mi < 4; mi++)
#pragma unroll
                for (int kc = 0; kc < 2; kc++)
                    vf[mi][kc] = *(const bf16x8*)(Vh + (size_t)(mi * 16 + l15) * SEQ + k0 + kc * 32 + quad * 8);

            // prefetch next K tile (in flight across softmax + PV)
            if (tk + 4 < ntiles) {
                const int k0p = k0 + 256;
#pragma unroll
                for (int ni = 0; ni < 4; ni++)
#pragma unroll
                    for (int kc = 0; kc < 2; kc++)
                        kfn[ni][kc] = *(const bf16x8*)(Kh + (size_t)(k0p + ni * 16 + l15) * DHEAD + kc * 32 + quad * 8);
            }

            if (k0 + 63 > q0) {   // diagonal tiles: mask kcol > q
#pragma unroll
                for (int ni = 0; ni < 4; ni++)
#pragma unroll
                    for (int qh = 0; qh < 2; qh++) {
                        const int q = q0 + qh * 16 + l15;
#pragma unroll
                        for (int r = 0; r < 4; r++) {
                            const int kcol = k0 + ni * 16 + quad * 4 + r;
                            if (kcol > q) sc[ni][qh][r] = -1e30f;
                        }
                    }
            }

            // Online softmax: 16-reg in-register tree + 2 cross-quad shfl
#pragma unroll
            for (int qh = 0; qh < 2; qh++) {
                float mx = sc[0][qh][0];
#pragma unroll
                for (int ni = 0; ni < 4; ni++)
#pragma unroll
                    for (int r = 0; r < 4; r++) mx = fmaxf(mx, sc[ni][qh][r]);
                mx = fmaxf(mx, __shfl_xor(mx, 16));
                mx = fmaxf(mx, __shfl_xor(mx, 32));
                const float mnew  = fmaxf(mq[qh], mx);
                const float alpha = exp2f(mq[qh] - mnew);
                mq[qh] = mnew;
                float sum = 0.0f;
#pragma unroll
                for (int ni = 0; ni < 4; ni++)
#pragma unroll
                    for (int r = 0; r < 4; r++) {
                        float p = exp2f(sc[ni][qh][r] - mnew);
                        sc[ni][qh][r] = p;
                        sum += p;
                    }
                sum += __shfl_xor(sum, 16);
                sum += __shfl_xor(sum, 32);
                lq[qh] = lq[qh] * alpha + sum;
#pragma unroll
                for (int mi = 0; mi < 4; mi++)
#pragma unroll
                    for (int r = 0; r < 4; r++) o[qh][mi][r] *= alpha;
                // P[q][kcol] bf16, packed b64 writes
#pragma unroll
                for (int ni = 0; ni < 4; ni++) {
                    union { unsigned short u[4]; uint2 v; } pk;
#pragma unroll
                    for (int r = 0; r < 4; r++) pk.u[r] = f2bf(sc[ni][qh][r]);
                    *(uint2*)(Pw + (qh * 16 + l15) * 72 + ni * 16 + quad * 4) = pk.v;
                }
            }

            // P^T as B-operand: lane n=l15 -> q, k=quad*8+j -> kcol
            bf16x8 pf[2][2];
#pragma unroll
            for (int qh = 0; qh < 2; qh++)
#pragma unroll
                for (int kc = 0; kc < 2; kc++)
                    pf[qh][kc] = *(const bf16x8*)(Pw + (qh * 16 + l15) * 72 + kc * 32 + quad * 8);

#pragma unroll
            for (int qh = 0; qh < 2; qh++)
#pragma unroll
                for (int mi = 0; mi < 4; mi++)
#pragma unroll
                    for (int kc = 0; kc < 2; kc++)
                        o[qh][mi] = __builtin_amdgcn_mfma_f32_16x16x32_bf16(
                            vf[mi][kc], pf[qh][kc], o[qh][mi], 0, 0, 0);
        }

        __syncthreads();   // all waves done with P region (O region overlays it)

        // dump partials: O^T[w][d][q], m/l[w][q]
#pragma unroll
        for (int qh = 0; qh < 2; qh++)
#pragma unroll
            for (int mi = 0; mi < 4; mi++)
#pragma unroll
                for (int r = 0; r < 4; r++)
                    Old[(w * 64 + mi * 16 + quad * 4 + r) * 36 + qh * 16 + l15] = o[qh][mi][r];
        if (quad == 0) {
#pragma unroll
            for (int qh = 0; qh < 2; qh++) {
                Mld[w * 32 + qh * 16 + l15] = mq[qh];
                Lld[w * 32 + qh * 16 + l15] = lq[qh];
            }
        }
        __syncthreads();

        // merge: wave w owns d-rows [w*16, w*16+16)
#pragma unroll
        for (int qh = 0; qh < 2; qh++) {
            const int q = qh * 16 + l15;
            float m4[4], l4[4];
#pragma unroll
            for (int ws = 0; ws < 4; ws++) { m4[ws] = Mld[ws * 32 + q]; l4[ws] = Lld[ws * 32 + q]; }
            const float mmax = fmaxf(fmaxf(m4[0], m4[1]), fmaxf(m4[2], m4[3]));
            float aw[4], ltot = 0.0f;
#pragma unroll
            for (int ws = 0; ws < 4; ws++) { aw[ws] = exp2f(m4[ws] - mmax); ltot += aw[ws] * l4[ws]; }
            const float inv = 1.0f / ltot;
            union { unsigned short u[4]; uint2 v; } pk;
#pragma unroll
            for (int r = 0; r < 4; r++) {
                const int d = w * 16 + quad * 4 + r;
                float a = 0.0f;
#pragma unroll
                for (int ws = 0; ws < 4; ws++) a += aw[ws] * Old[(ws * 64 + d) * 36 + q];
                pk.u[r] = f2bf(a * inv);
            }
            *(uint2*)(AO + (size_t)(q0 + q) * DMODEL + h * DHEAD + w * 16 + quad * 4) = pk.v;
        }
        __syncthreads();   // merge reads done before next phase reuses P region
    }
}

// ---------------------------------------------------------------------------
extern "C" void kernel_launch(void* const* d_in, const int* in_sizes, int n_in,
                              void* d_out, int out_size, void* d_ws, size_t ws_size,
                              hipStream_t stream)
{
    (void)in_sizes; (void)n_in; (void)out_size; (void)ws_size;

    const float* x     = (const float*)d_in[0]; // [4096][768] fp32
    const float* W_in  = (const float*)d_in[1]; // [2304][768] fp32
    const float* b_in  = (const float*)d_in[2]; // [2304] fp32
    const float* W_out = (const float*)d_in[3]; // [768][768] fp32
    const float* b_out = (const float*)d_in[4]; // [768] fp32
    float* out = (float*)d_out;                 // [4096][768] fp32

    char* p = (char*)d_ws;
    const size_t sz_sd = (size_t)SEQ * DMODEL * 2;          // 6.29 MB
    unsigned short* qs = (unsigned short*)p; p += sz_sd;    // [12][4096][64]
    unsigned short* ks = (unsigned short*)p; p += sz_sd;    // [12][4096][64]
    unsigned short* vt = (unsigned short*)p; p += sz_sd;    // [12][64][4096]
    unsigned short* ao = (unsigned short*)p; p += sz_sd;    // [4096][768]

    // 1) qkv projection; Q scaled, V written pre-transposed
    gemm_bt_kernel<0><<<dim3(18, 32), 256, 0, stream>>>(
        (const void*)x, W_in, b_in, DMODEL, 3 * DMODEL, qs, ks, vt, nullptr);
    // 2) causal flash attention (S^T, split-K, paired q-tiles, K-prefetch)
    attn_kernel<<<dim3(64, 12), 256, 0, stream>>>(qs, ks, vt, ao);
    // 3) output projection
    gemm_bt_kernel<1><<<dim3(6, 32), 256, 0, stream>>>(
        (const void*)ao, W_out, b_out, DMODEL, DMODEL, nullptr, nullptr, nullptr, out);
}

// Round 6
// 263.892 us; speedup vs baseline: 1.5062x; 1.0360x over previous
//
#include <hip/hip_runtime.h>
#include <stdint.h>
#include <stddef.h>

// Problem constants
#define SEQ    4096
#define DMODEL 768
#define NHEAD  12
#define DHEAD  64
// (1/sqrt(DHEAD)) * log2(e): fold softmax scale AND base-2 conversion into Q
#define QSCALE 0.18033688011112042f

typedef __attribute__((ext_vector_type(8))) short bf16x8;   // 8 bf16 = 4 VGPRs
typedef __attribute__((ext_vector_type(4))) float f32x4;    // MFMA acc

__device__ __forceinline__ unsigned short f2bf(float f) {
    union { float f; unsigned int u; } v; v.f = f;
    unsigned int r = v.u + 0x7FFFu + ((v.u >> 16) & 1u);   // RNE
    return (unsigned short)(r >> 16);
}
__device__ __forceinline__ float bf2f(unsigned short b) {
    union { float f; unsigned int u; } v; v.u = ((unsigned int)b) << 16;
    return v.f;
}
// 8 consecutive fp32 -> bf16x8 (RNE)
__device__ __forceinline__ bf16x8 ld8f_bf(const float* p) {
    f32x4 lo = *(const f32x4*)p;
    f32x4 hi = *(const f32x4*)(p + 4);
    union { bf16x8 v; unsigned short u[8]; } pk;
#pragma unroll
    for (int j = 0; j < 4; j++) { pk.u[j] = f2bf(lo[j]); pk.u[4 + j] = f2bf(hi[j]); }
    return pk.v;
}

// ---------------------------------------------------------------------------
// Packed fragment-major workspace layouts (per head, per 64-col k-tile or
// 32-row q-tile), so attention's global loads are contiguous 1KB wave-loads:
//   Qp[h][q>>5][(qh*2+kc)][lane][8]   lane = ((d&31)>>3)*16 + (q&15), j = d&7
//   Kp[h][s>>6][(ni*2+kc)][lane][8]   lane = ((d&31)>>3)*16 + (s&15), j = d&7
//   Vp[h][s>>6][(mi*2+kc)][lane][8]   lane = (((s&31)>>3)*16) + (d&15), j = s&7
// ---------------------------------------------------------------------------

// ---------------------------------------------------------------------------
// GEMM (BT layout): C[M,N] = A[M,K] * B[N,K]^T + bias.  External I/O = fp32.
// 128x128 block, BK=64, 256 threads = 4 waves (2x2), each wave 64x64.
// EPI=0: scatter into packed Qp (scaled) / Kp / Vp fragment-major bf16.
// EPI=1: A internal bf16; B,bias fp32; output fp32 [M,N].
// ---------------------------------------------------------------------------
template <int EPI>
__global__ __launch_bounds__(256, 2) void gemm_bt_kernel(
    const void* __restrict__ Av,
    const float* __restrict__ B,
    const float* __restrict__ bias,
    int K, int N,
    unsigned short* __restrict__ oq,
    unsigned short* __restrict__ ok,
    unsigned short* __restrict__ ov,
    float* __restrict__ ob)
{
    __shared__ __align__(16) unsigned short As[128 * 72];  // stride 72: conflict-free
    __shared__ __align__(16) unsigned short Bs[128 * 72];

    const int t    = threadIdx.x;
    const int lane = t & 63;
    const int wave = t >> 6;
    const int l15  = lane & 15;
    const int quad = lane >> 4;
    const int wm   = wave >> 1;
    const int wn   = wave & 1;
    const int m0   = blockIdx.y * 128;
    const int n0   = blockIdx.x * 128;

    f32x4 acc[4][4] = {};

    for (int k0 = 0; k0 < K; k0 += 64) {
        bf16x8 ra[4], rb[4];
#pragma unroll
        for (int c = 0; c < 4; c++) {
            int g = c * 256 + t;
            int row = g >> 3, cg = g & 7;
            size_t offa = (size_t)(m0 + row) * K + (k0 + cg * 8);
            size_t offb = (size_t)(n0 + row) * K + (k0 + cg * 8);
            if (EPI == 1) ra[c] = *(const bf16x8*)((const unsigned short*)Av + offa);
            else          ra[c] = ld8f_bf((const float*)Av + offa);
            rb[c] = ld8f_bf(B + offb);
        }
        __syncthreads();   // previous iteration's LDS reads done
#pragma unroll
        for (int c = 0; c < 4; c++) {
            int g = c * 256 + t;
            int row = g >> 3, cg = g & 7;
            *(bf16x8*)(As + row * 72 + cg * 8) = ra[c];
            *(bf16x8*)(Bs + row * 72 + cg * 8) = rb[c];
        }
        __syncthreads();
#pragma unroll
        for (int ki = 0; ki < 2; ki++) {
            bf16x8 af[4], bfr[4];
#pragma unroll
            for (int mi = 0; mi < 4; mi++)
                af[mi] = *(const bf16x8*)(As + (wm * 64 + mi * 16 + l15) * 72 + ki * 32 + quad * 8);
#pragma unroll
            for (int ni = 0; ni < 4; ni++)
                bfr[ni] = *(const bf16x8*)(Bs + (wn * 64 + ni * 16 + l15) * 72 + ki * 32 + quad * 8);
#pragma unroll
            for (int mi = 0; mi < 4; mi++)
#pragma unroll
                for (int ni = 0; ni < 4; ni++)
                    acc[mi][ni] = __builtin_amdgcn_mfma_f32_16x16x32_bf16(
                        af[mi], bfr[ni], acc[mi][ni], 0, 0, 0);
        }
    }

    // Epilogue. C/D layout: col = lane&15, row = quad*4 + reg.
    if (EPI == 0) {
        const int nbase = n0 + wn * 64;            // multiple of 64 -> head-aligned
        const int which = nbase / DMODEL;          // 0=q 1=k 2=v (uniform per wave)
        const int hh    = (nbase % DMODEL) >> 6;   // head (uniform per wave)
        const size_t hoff = (size_t)hh * SEQ * 64; // u16 elems per head
        if (which == 0) {
#pragma unroll
            for (int ni = 0; ni < 4; ni++) {
                const int d  = ni * 16 + l15;
                const float bv = bias[nbase + d];
                const int kcq  = d >> 5;
                const int lnq  = ((d & 31) >> 3) * 16;   // + (q&15)
                const int jq   = d & 7;
#pragma unroll
                for (int mi = 0; mi < 4; mi++) {
                    const int mb = m0 + wm * 64 + mi * 16 + quad * 4;
#pragma unroll
                    for (int r = 0; r < 4; r++) {
                        const int q = mb + r;
                        const size_t off = hoff + (size_t)(q >> 5) * 2048
                            + (((q & 31) >> 4) * 2 + kcq) * 512
                            + (lnq + (q & 15)) * 8 + jq;
                        oq[off] = f2bf((acc[mi][ni][r] + bv) * QSCALE);
                    }
                }
            }
        } else if (which == 1) {
#pragma unroll
            for (int ni = 0; ni < 4; ni++) {
                const int d  = ni * 16 + l15;
                const float bv = bias[nbase + d];
                const int kck  = d >> 5;
                const int lnk  = ((d & 31) >> 3) * 16;
                const int jk   = d & 7;
#pragma unroll
                for (int mi = 0; mi < 4; mi++) {
                    const int mb = m0 + wm * 64 + mi * 16 + quad * 4;
#pragma unroll
                    for (int r = 0; r < 4; r++) {
                        const int s = mb + r;
                        const size_t off = hoff + (size_t)(s >> 6) * 4096
                            + ((((s & 63) >> 4)) * 2 + kck) * 512
                            + (lnk + (s & 15)) * 8 + jk;
                        ok[off] = f2bf(acc[mi][ni][r] + bv);
                    }
                }
            }
        } else {
            // V packed: 4 consecutive s (r=0..3) land in one lane-block -> uint2
#pragma unroll
            for (int ni = 0; ni < 4; ni++) {
                const int d  = ni * 16 + l15;
                const float bv = bias[nbase + d];
                const int miv = (d & 63) >> 4;
                const int l15v = d & 15;
#pragma unroll
                for (int mi = 0; mi < 4; mi++) {
                    const int mb = m0 + wm * 64 + mi * 16 + quad * 4;  // s base, 4-aligned
                    const size_t off = hoff + (size_t)(mb >> 6) * 4096
                        + (miv * 2 + ((mb & 63) >> 5)) * 512
                        + (((mb & 31) >> 3) * 16 + l15v) * 8 + (mb & 7);
                    union { unsigned short u[4]; uint2 v; } pk;
#pragma unroll
                    for (int r = 0; r < 4; r++) pk.u[r] = f2bf(acc[mi][ni][r] + bv);
                    *(uint2*)(ov + off) = pk.v;
                }
            }
        }
    } else {
#pragma unroll
        for (int ni = 0; ni < 4; ni++) {
            const int n  = n0 + wn * 64 + ni * 16 + l15;
            const float bv = bias[n];
#pragma unroll
            for (int mi = 0; mi < 4; mi++) {
                const int mb = m0 + wm * 64 + mi * 16 + quad * 4;
#pragma unroll
                for (int r = 0; r < 4; r++)
                    ob[(size_t)(mb + r) * N + n] = acc[mi][ni][r] + bv;
            }
        }
    }
}

// ---------------------------------------------------------------------------
// Flash attention, causal, S^T formulation, intra-block split-K (4 waves),
// paired q-tiles (block px does q-tiles 127-px then px: constant total work).
// All Q/K/V global loads are contiguous 1KB wave-loads (packed layouts).
// K prefetched one tile ahead. O partials merged via LDS in bf16.
// ---------------------------------------------------------------------------
__global__ __launch_bounds__(256) void attn_kernel(
    const unsigned short* __restrict__ Qp,
    const unsigned short* __restrict__ Kp,
    const unsigned short* __restrict__ Vp,
    unsigned short* __restrict__ AO)
{
    // 0..18432   : P staging, 4 waves x (32 x 72) u16   (loop phase)
    // 0..20480   : O partials u16 [4 w][64 d][40 q]      (merge phase)
    // 20480..21504: m [4][32] f32 then l [4][32] f32
    __shared__ __align__(16) char LB[21504];

    const int t    = threadIdx.x;
    const int lane = t & 63;
    const int w    = t >> 6;      // k-split wave id
    const int l15  = lane & 15;
    const int quad = lane >> 4;
    const int h    = blockIdx.y;
    const int px   = blockIdx.x;  // 0..63

    unsigned short* Pw  = (unsigned short*)LB + w * 32 * 72;
    unsigned short* Old = (unsigned short*)LB;
    float*          Mld = (float*)(LB + 20480);
    float*          Lld = Mld + 4 * 32;

    const unsigned short* Qh = Qp + (size_t)h * SEQ * 64;
    const unsigned short* Kh = Kp + (size_t)h * SEQ * 64;
    const unsigned short* Vh = Vp + (size_t)h * SEQ * 64;

#pragma unroll 1
    for (int phase = 0; phase < 2; phase++) {
        const int qt = (phase == 0 ? (127 - px) : px);
        const int q0 = qt * 32;

        // Q fragments: contiguous 1KB per (qh,kc)
        bf16x8 qf[2][2];
#pragma unroll
        for (int qh = 0; qh < 2; qh++)
#pragma unroll
            for (int kc = 0; kc < 2; kc++)
                qf[qh][kc] = *(const bf16x8*)(Qh + (size_t)qt * 2048 + (qh * 2 + kc) * 512 + lane * 8);

        f32x4 o[2][4] = {};            // O^T partial: col=q(l15), row=d
        float mq[2] = { -1e30f, -1e30f };
        float lq[2] = { 0.0f, 0.0f };

        const int ntiles = (q0 + 95) >> 6;

        // K prefetch (contiguous 1KB per fragment)
        bf16x8 kfn[4][2];
        if (w < ntiles) {
#pragma unroll
            for (int ni = 0; ni < 4; ni++)
#pragma unroll
                for (int kc = 0; kc < 2; kc++)
                    kfn[ni][kc] = *(const bf16x8*)(Kh + (size_t)w * 4096 + (ni * 2 + kc) * 512 + lane * 8);
        }

        for (int tk = w; tk < ntiles; tk += 4) {
            const int k0 = tk * 64;

            // Sc^T[ni][qh]: C row = kcol (quad*4+r), col = q (l15)
            f32x4 sc[4][2] = {};
#pragma unroll
            for (int ni = 0; ni < 4; ni++)
#pragma unroll
                for (int qh = 0; qh < 2; qh++)
#pragma unroll
                    for (int kc = 0; kc < 2; kc++)
                        sc[ni][qh] = __builtin_amdgcn_mfma_f32_16x16x32_bf16(
                            kfn[ni][kc], qf[qh][kc], sc[ni][qh], 0, 0, 0);

            // V fragments for this tile (1KB contiguous each; hidden by softmax)
            bf16x8 vf[4][2];
#pragma unroll
            for (int mi = 0; mi < 4; mi++)
#pragma unroll
                for (int kc = 0; kc < 2; kc++)
                    vf[mi][kc] = *(const bf16x8*)(Vh + (size_t)tk * 4096 + (mi * 2 + kc) * 512 + lane * 8);

            // prefetch next K tile
            if (tk + 4 < ntiles) {
#pragma unroll
                for (int ni = 0; ni < 4; ni++)
#pragma unroll
                    for (int kc = 0; kc < 2; kc++)
                        kfn[ni][kc] = *(const bf16x8*)(Kh + (size_t)(tk + 4) * 4096 + (ni * 2 + kc) * 512 + lane * 8);
            }

            if (k0 + 63 > q0) {   // diagonal tiles: mask kcol > q
#pragma unroll
                for (int ni = 0; ni < 4; ni++)
#pragma unroll
                    for (int qh = 0; qh < 2; qh++) {
                        const int q = q0 + qh * 16 + l15;
#pragma unroll
                        for (int r = 0; r < 4; r++) {
                            const int kcol = k0 + ni * 16 + quad * 4 + r;
                            if (kcol > q) sc[ni][qh][r] = -1e30f;
                        }
                    }
            }

            // Online softmax, both qh interleaved; explicit trees.
            float mx0, mx1;
            {
                float a0[4], a1[4];
#pragma unroll
                for (int ni = 0; ni < 4; ni++) {
                    a0[ni] = fmaxf(fmaxf(sc[ni][0][0], sc[ni][0][1]), fmaxf(sc[ni][0][2], sc[ni][0][3]));
                    a1[ni] = fmaxf(fmaxf(sc[ni][1][0], sc[ni][1][1]), fmaxf(sc[ni][1][2], sc[ni][1][3]));
                }
                mx0 = fmaxf(fmaxf(a0[0], a0[1]), fmaxf(a0[2], a0[3]));
                mx1 = fmaxf(fmaxf(a1[0], a1[1]), fmaxf(a1[2], a1[3]));
            }
            {
                float x0 = __shfl_xor(mx0, 16), x1 = __shfl_xor(mx1, 16);
                mx0 = fmaxf(mx0, x0); mx1 = fmaxf(mx1, x1);
                x0 = __shfl_xor(mx0, 32); x1 = __shfl_xor(mx1, 32);
                mx0 = fmaxf(mx0, x0); mx1 = fmaxf(mx1, x1);
            }
            const float mn0 = fmaxf(mq[0], mx0), mn1 = fmaxf(mq[1], mx1);
            const float al0 = exp2f(mq[0] - mn0), al1 = exp2f(mq[1] - mn1);
            mq[0] = mn0; mq[1] = mn1;
#pragma unroll
            for (int ni = 0; ni < 4; ni++)
#pragma unroll
                for (int r = 0; r < 4; r++) {
                    sc[ni][0][r] = exp2f(sc[ni][0][r] - mn0);
                    sc[ni][1][r] = exp2f(sc[ni][1][r] - mn1);
                }
            float s0, s1;
            {
                float b0[4], b1[4];
#pragma unroll
                for (int ni = 0; ni < 4; ni++) {
                    b0[ni] = (sc[ni][0][0] + sc[ni][0][1]) + (sc[ni][0][2] + sc[ni][0][3]);
                    b1[ni] = (sc[ni][1][0] + sc[ni][1][1]) + (sc[ni][1][2] + sc[ni][1][3]);
                }
                s0 = (b0[0] + b0[1]) + (b0[2] + b0[3]);
                s1 = (b1[0] + b1[1]) + (b1[2] + b1[3]);
            }
            {
                float x0 = __shfl_xor(s0, 16), x1 = __shfl_xor(s1, 16);
                s0 += x0; s1 += x1;
                x0 = __shfl_xor(s0, 32); x1 = __shfl_xor(s1, 32);
                s0 += x0; s1 += x1;
            }
            lq[0] = lq[0] * al0 + s0;
            lq[1] = lq[1] * al1 + s1;
#pragma unroll
            for (int mi = 0; mi < 4; mi++)
#pragma unroll
                for (int r = 0; r < 4; r++) { o[0][mi][r] *= al0; o[1][mi][r] *= al1; }
            // P[q][kcol] bf16, packed b64 writes
#pragma unroll
            for (int qh = 0; qh < 2; qh++)
#pragma unroll
                for (int ni = 0; ni < 4; ni++) {
                    union { unsigned short u[4]; uint2 v; } pk;
#pragma unroll
                    for (int r = 0; r < 4; r++) pk.u[r] = f2bf(sc[ni][qh][r]);
                    *(uint2*)(Pw + (qh * 16 + l15) * 72 + ni * 16 + quad * 4) = pk.v;
                }

            // P^T as B-operand: lane n=l15 -> q, k=quad*8+j -> kcol
            bf16x8 pf[2][2];
#pragma unroll
            for (int qh = 0; qh < 2; qh++)
#pragma unroll
                for (int kc = 0; kc < 2; kc++)
                    pf[qh][kc] = *(const bf16x8*)(Pw + (qh * 16 + l15) * 72 + kc * 32 + quad * 8);

#pragma unroll
            for (int qh = 0; qh < 2; qh++)
#pragma unroll
                for (int mi = 0; mi < 4; mi++)
#pragma unroll
                    for (int kc = 0; kc < 2; kc++)
                        o[qh][mi] = __builtin_amdgcn_mfma_f32_16x16x32_bf16(
                            vf[mi][kc], pf[qh][kc], o[qh][mi], 0, 0, 0);
        }

        __syncthreads();   // all waves done with P region (O region overlays it)

        // dump partials (bf16): Old[w][d][q], m/l[w][q] f32
#pragma unroll
        for (int qh = 0; qh < 2; qh++)
#pragma unroll
            for (int mi = 0; mi < 4; mi++)
#pragma unroll
                for (int r = 0; r < 4; r++)
                    Old[(w * 64 + mi * 16 + quad * 4 + r) * 40 + qh * 16 + l15] = f2bf(o[qh][mi][r]);
        if (quad == 0) {
#pragma unroll
            for (int qh = 0; qh < 2; qh++) {
                Mld[w * 32 + qh * 16 + l15] = mq[qh];
                Lld[w * 32 + qh * 16 + l15] = lq[qh];
            }
        }
        __syncthreads();

        // merge: wave w owns d-rows [w*16, w*16+16)
#pragma unroll
        for (int qh = 0; qh < 2; qh++) {
            const int q = qh * 16 + l15;
            float m4[4], l4[4];
#pragma unroll
            for (int ws = 0; ws < 4; ws++) { m4[ws] = Mld[ws * 32 + q]; l4[ws] = Lld[ws * 32 + q]; }
            const float mmax = fmaxf(fmaxf(m4[0], m4[1]), fmaxf(m4[2], m4[3]));
            float aw[4], ltot = 0.0f;
#pragma unroll
            for (int ws = 0; ws < 4; ws++) { aw[ws] = exp2f(m4[ws] - mmax); ltot += aw[ws] * l4[ws]; }
            const float inv = 1.0f / ltot;
            union { unsigned short u[4]; uint2 v; } pk;
#pragma unroll
            for (int r = 0; r < 4; r++) {
                const int d = w * 16 + quad * 4 + r;
                float a = 0.0f;
#pragma unroll
                for (int ws = 0; ws < 4; ws++) a += aw[ws] * bf2f(Old[(ws * 64 + d) * 40 + q]);
                pk.u[r] = f2bf(a * inv);
            }
            *(uint2*)(AO + (size_t)(q0 + q) * DMODEL + h * DHEAD + w * 16 + quad * 4) = pk.v;
        }
        __syncthreads();   // merge reads done before next phase reuses P region
    }
}

// ---------------------------------------------------------------------------
extern "C" void kernel_launch(void* const* d_in, const int* in_sizes, int n_in,
                              void* d_out, int out_size, void* d_ws, size_t ws_size,
                              hipStream_t stream)
{
    (void)in_sizes; (void)n_in; (void)out_size; (void)ws_size;

    const float* x     = (const float*)d_in[0]; // [4096][768] fp32
    const float* W_in  = (const float*)d_in[1]; // [2304][768] fp32
    const float* b_in  = (const float*)d_in[2]; // [2304] fp32
    const float* W_out = (const float*)d_in[3]; // [768][768] fp32
    const float* b_out = (const float*)d_in[4]; // [768] fp32
    float* out = (float*)d_out;                 // [4096][768] fp32

    char* p = (char*)d_ws;
    const size_t sz_sd = (size_t)SEQ * DMODEL * 2;          // 6.29 MB
    unsigned short* qp = (unsigned short*)p; p += sz_sd;    // packed Q
    unsigned short* kp = (unsigned short*)p; p += sz_sd;    // packed K
    unsigned short* vp = (unsigned short*)p; p += sz_sd;    // packed V
    unsigned short* ao = (unsigned short*)p; p += sz_sd;    // [4096][768]

    // 1) qkv projection; outputs in MFMA-fragment-major packed layouts
    gemm_bt_kernel<0><<<dim3(18, 32), 256, 0, stream>>>(
        (const void*)x, W_in, b_in, DMODEL, 3 * DMODEL, qp, kp, vp, nullptr);
    // 2) causal flash attention (S^T, split-K, paired q-tiles, coalesced loads)
    attn_kernel<<<dim3(64, 12), 256, 0, stream>>>(qp, kp, vp, ao);
    // 3) output projection
    gemm_bt_kernel<1><<<dim3(6, 32), 256, 0, stream>>>(
        (const void*)ao, W_out, b_out, DMODEL, DMODEL, nullptr, nullptr, nullptr, out);
}